// Round 12
// baseline (81.110 us; speedup 1.0000x reference)
//
#include <hip/hip_runtime.h>
#include <hip/hip_bf16.h>

typedef __attribute__((ext_vector_type(4))) unsigned int uint4v;
typedef __attribute__((ext_vector_type(8))) short short8;
typedef __attribute__((ext_vector_type(16))) float floatx16;

#define NROW 148
#define ROWB (20*512)                    // 10240 B per pad row (20 chunk-cols x 32ch x 16B)
#define BB   ((size_t)NROW*ROWB)         // per-batch bytes (1.51 MB)
#define STATS_OFF ((size_t)8*BB)         // 12,124,160
#define LDS_A_ROWS 38
#define ABUF (LDS_A_ROWS*2048)           // 77824
#define LDS_BYTES (2*ABUF)               // 155648 (A double-buffered; B stays in regs)

__device__ __forceinline__ unsigned short f2b(float f){
  unsigned int u = __float_as_uint(f);
  return (unsigned short)((u + 0x7fffu + ((u >> 16) & 1u)) >> 16);  // RNE
}

// lgkm-only barrier: LDS ops drained; global loads stay in flight across it.
#define BAR_LGKM() do { \
  __builtin_amdgcn_sched_barrier(0); \
  asm volatile("s_waitcnt lgkmcnt(0)" ::: "memory"); \
  __builtin_amdgcn_s_barrier(); \
  __builtin_amdgcn_sched_barrier(0); \
} while(0)

// ---------------- Kernel 1: per-(b,c) mean/scale ----------------
__global__ __launch_bounds__(256) void k_stat(const float* __restrict__ x,
                                              float* __restrict__ stats){
  int bid = blockIdx.x;                  // = b*32 + c
  int t = threadIdx.x;
  const float* xc = x + ((size_t)bid << 14);
  float s = 0.f, ss = 0.f;
  #pragma unroll 4
  for (int k = 0; k < 64; ++k){
    float v = xc[t + (k << 8)];
    s += v; ss += v*v;
  }
  #pragma unroll
  for (int m = 32; m >= 1; m >>= 1){
    s  += __shfl_xor(s, m);
    ss += __shfl_xor(ss, m);
  }
  __shared__ float rs[4], rss[4];
  int wv = t >> 6, l = t & 63;
  if (l == 0){ rs[wv] = s; rss[wv] = ss; }
  __syncthreads();
  if (t == 0){
    float S  = rs[0]+rs[1]+rs[2]+rs[3];
    float SS = rss[0]+rss[1]+rss[2]+rss[3];
    float mean = S * (1.f/16384.f);
    float var  = (SS - S*mean) * (1.f/16383.f);   // ddof=1
    float sd = sqrtf(fmaxf(var, 0.f));
    stats[bid*2]   = mean;
    stats[bid*2+1] = (sd < 1e-9f) ? 0.f : 1.f/(sd*128.f);  // 1/(std*sqrt(16384))
  }
}

// ---------------- Kernel 2: standardize + chunk-interleaved pad ----------------
// pad chunk (b, r, col, ch), elements e=0..7:  xs_std[b][ch][(r-10)%128][(8*col+e)%128]
__global__ __launch_bounds__(512) void k_pack(const float* __restrict__ x,
                                              const float* __restrict__ stats,
                                              unsigned char* __restrict__ pad){
  __shared__ float rowbuf[32*129];       // +1 f32 pad per channel row -> conflict-free
  int bid = blockIdx.x;
  int b = bid & 7, rg = bid >> 3;        // rg 0..36, rows 4rg..4rg+3
  int t = threadIdx.x;
  int ch = t >> 4, xq = t & 15;
  float mean  = stats[(b*32 + ch)*2];
  float scale = stats[(b*32 + ch)*2 + 1];
  const float* xc = x + ((size_t)(b*32 + ch) << 14);
  for (int rr = 0; rr < 4; ++rr){
    int r = rg*4 + rr;
    int sy = (r + 118) & 127;            // (r-10) mod 128
    const float* src = xc + (sy << 7) + (xq << 3);
    float4 v0 = *(const float4*)src;
    float4 v1 = *(const float4*)(src + 4);
    float* rb = rowbuf + ch*129 + (xq << 3);
    rb[0] = (v0.x-mean)*scale; rb[1] = (v0.y-mean)*scale;
    rb[2] = (v0.z-mean)*scale; rb[3] = (v0.w-mean)*scale;
    rb[4] = (v1.x-mean)*scale; rb[5] = (v1.y-mean)*scale;
    rb[6] = (v1.z-mean)*scale; rb[7] = (v1.w-mean)*scale;
    __syncthreads();
    #pragma unroll
    for (int k = 0; k < 2; ++k){
      int q = t + (k << 9);
      if (q < 640){
        int col = q >> 5, cq = q & 31;
        const float* rbq = rowbuf + cq*129;
        unsigned int d[4];
        #pragma unroll
        for (int e = 0; e < 4; ++e){
          unsigned int lo = f2b(rbq[(8*col + 2*e)     & 127]);
          unsigned int hi = f2b(rbq[(8*col + 2*e + 1) & 127]);
          d[e] = lo | (hi << 16);
        }
        uint4v ov = {d[0], d[1], d[2], d[3]};
        *(uint4v*)(pad + ((size_t)(b*148 + r)*20 + col)*512 + cq*16) = ov;
      }
    }
    __syncthreads();
  }
}

// ---------------- Kernel 3: shifted Gram via 32x32x16 MFMA ----------------
// 256 blocks = (cg 0..31) x (b 0..7), 512 thr = 8 waves (kq 0..3 y-quarter, ks 0..1 col-half)
// A: dx-pre-shifted, double-buffered LDS, 1 lgkm-only barrier/tile.
// B: depth-4 register queue (4 | 8 steps/tile -> slot mapping is tile-invariant).
#define WW(k3, idx) (aw[k3][(idx)>>2][(idx)&3])
#define SHIFT_STORE(OFS, ODD) \
  { _Pragma("unroll") \
    for (int k3 = 0; k3 < 3; ++k3){ \
      int pid = tid + (k3 << 9); \
      if (pid < 1216){ \
        char* dst = Asw + (pid >> 5)*2048 + (pid & 31)*16; \
        _Pragma("unroll") \
        for (int c = 0; c < 4; ++c){ \
          unsigned int o0,o1,o2,o3; \
          if (ODD){ \
            o0 = (WW(k3,4*c+OFS+0)>>16)|(WW(k3,4*c+OFS+1)<<16); \
            o1 = (WW(k3,4*c+OFS+1)>>16)|(WW(k3,4*c+OFS+2)<<16); \
            o2 = (WW(k3,4*c+OFS+2)>>16)|(WW(k3,4*c+OFS+3)<<16); \
            o3 = (WW(k3,4*c+OFS+3)>>16)|(WW(k3,4*c+OFS+4)<<16); \
          } else { \
            o0 = WW(k3,4*c+OFS+0); o1 = WW(k3,4*c+OFS+1); \
            o2 = WW(k3,4*c+OFS+2); o3 = WW(k3,4*c+OFS+3); \
          } \
          uint4v ov = {o0,o1,o2,o3}; \
          *(uint4v*)(dst + c*512) = ov; \
        } \
      } \
    } }
#define DO_SHIFT_STORE() \
  switch (r2){ \
    case 0: SHIFT_STORE(0, 0); break; \
    case 1: SHIFT_STORE(0, 1); break; \
    case 2: SHIFT_STORE(1, 0); break; \
    case 3: SHIFT_STORE(1, 1); break; \
    case 4: SHIFT_STORE(2, 0); break; \
    case 5: SHIFT_STORE(2, 1); break; \
    case 6: SHIFT_STORE(3, 0); break; \
    case 7: SHIFT_STORE(3, 1); break; \
  }

__global__ __launch_bounds__(512, 1) void k_corr(const unsigned char* __restrict__ pad,
                                                 float* __restrict__ out){
  extern __shared__ char lds[];
  char* As = lds;                         // 2 x 38 rows x 2KB, dx-pre-shifted
  float* sf = (float*)lds;                // epilogue reuse (32KB)

  int bid = blockIdx.x;
  int b = bid & 7, cg = bid >> 3;
  int dx, d0;
  if (cg < 2){ dx = 0; d0 = cg << 2; }                  // dy groups {0..6}, {4..10}
  else { int q = cg - 2; dx = 1 + q/3; d0 = -10 + 7*(q - 3*(q/3)); }
  int r2 = dx & 7, cwoff = dx >> 3;

  int tid = threadIdx.x;
  int lane = tid & 63, wvi = tid >> 6;
  int ks = wvi & 1, kq = wvi >> 1;
  unsigned offF = (unsigned)((2*ks + (lane >> 5))*512 + (lane & 31)*16);

  const unsigned char* pb = pad + (size_t)b*BB;

  floatx16 acc[7];
  #pragma unroll
  for (int d = 0; d < 7; ++d) acc[d] = (floatx16)(0.0f);

  uint4v aw[3][5];
  auto issueA = [&](int tt){
    int rab = 32*(tt >> 2) + 10 + d0;     // A-region pad-row base (0..110)
    int cwb = 4*(tt & 3) + cwoff;
    #pragma unroll
    for (int k3 = 0; k3 < 3; ++k3){
      int pid = tid + (k3 << 9);
      if (pid < 1216){
        const unsigned char* g = pb + ((size_t)((rab + (pid >> 5))*20 + cwb))*512 + (pid & 31)*16;
        #pragma unroll
        for (int kk = 0; kk < 5; ++kk)
          aw[k3][kk] = *(const uint4v*)(g + kk*512);
      }
    }
  };
  auto pBaddr = [&](int tt)->const unsigned char*{
    return pb + ((size_t)((32*(tt >> 2) + 10 + kq*8)*20 + 4*(tt & 3) + 2*ks))*512
              + (unsigned)((lane >> 5)*512 + (lane & 31)*16);
  };

  // prologue: stage tile 0 into buf0, prefetch tile 1 regs, warm BQ rows 0..3 of tile 0
  issueA(0);
  { char* Asw = As; DO_SHIFT_STORE(); }
  issueA(1);
  short8 BQ[4];
  {
    const unsigned char* pB0 = pBaddr(0);
    #pragma unroll
    for (int k = 0; k < 4; ++k) BQ[k] = *(const short8*)(pB0 + (size_t)k*ROWB);
  }
  BAR_LGKM();

  for (int t = 0; t < 16; ++t){
    // stage tile t+1 into the other buffer (regs prefetched last iter; waits on their vmcnt)
    if (t < 15){ char* Asw = As + ((t+1)&1)*ABUF; DO_SHIFT_STORE(); }
    if (t < 14) issueA(t+2);
    // ---- compute tile t: A from LDS buf (t&1), B from register queue ----
    const char* Ab = As + (t&1)*ABUF + (kq*8)*2048 + offF;
    const unsigned char* pBc = pBaddr(t);
    const unsigned char* pBn = pBaddr(t+1);
    bool more = (t < 15);
    short8 ring[8];
    #pragma unroll
    for (int w = 0; w < 8; ++w) ring[w] = *(const short8*)(Ab + w*2048);
    __builtin_amdgcn_s_setprio(1);
    #pragma unroll
    for (int yl = 0; yl < 8; ++yl){
      short8 bf = BQ[yl & 3];
      #pragma unroll
      for (int d = 0; d < 7; ++d)
        acc[d] = __builtin_amdgcn_mfma_f32_32x32x16_bf16(ring[(yl+d)&7], bf, acc[d], 0, 0, 0);
      // refills AFTER the MFMAs: 4-step B slack, 2-step ring slack; slot map tile-invariant
      if (yl < 4)       BQ[yl & 3] = *(const short8*)(pBc + (size_t)(yl + 4)*ROWB);
      else if (more)    BQ[yl & 3] = *(const short8*)(pBn + (size_t)(yl - 4)*ROWB);
      if (yl < 6) ring[yl & 7] = *(const short8*)(Ab + (yl + 8)*2048);
    }
    __builtin_amdgcn_s_setprio(0);
    BAR_LGKM();                           // lgkm-only: aw/BQ global loads stay in flight
  }

  // ---- epilogue: 8-wave reduce per dy, triangle-routed stores ----
  int baseb = b * 232848;                 // 528*441
  #pragma unroll
  for (int d = 0; d < 7; ++d){
    #pragma unroll
    for (int r = 0; r < 16; ++r)
      sf[wvi*1024 + r*64 + lane] = acc[d][r];
    __syncthreads();
    int dy = d0 + d;
    #pragma unroll
    for (int k = 0; k < 2; ++k){
      int p = tid + (k << 9);
      float v = 0.f;
      #pragma unroll
      for (int w = 0; w < 8; ++w) v += sf[w*1024 + p];
      int reg = p >> 6, ln = p & 63;
      int i = (reg & 3) + 8*(reg >> 2) + 4*(ln >> 5);   // C row (M = channel i, shifted operand)
      int j = ln & 31;                                   // C col (N = channel j)
      if (i <= j){
        int pp = i*(65 - i)/2 + (j - i);
        out[baseb + pp*441 + (10+dy)*21 + (10+dx)] = v;
        if (i == j && (dy != 0 || dx != 0))
          out[baseb + pp*441 + (10-dy)*21 + (10-dx)] = v;   // autocorr symmetry
      } else {
        int pp = j*(65 - j)/2 + (i - j);
        out[baseb + pp*441 + (10-dy)*21 + (10-dx)] = v;     // pair (j,i) at (-dy,-dx)
      }
    }
    __syncthreads();
  }
}

extern "C" void kernel_launch(void* const* d_in, const int* in_sizes, int n_in,
                              void* d_out, int out_size, void* d_ws, size_t ws_size,
                              hipStream_t stream){
  const float* x = (const float*)d_in[0];
  unsigned char* pad = (unsigned char*)d_ws;             // 12.12 MB
  float* stats = (float*)((char*)d_ws + STATS_OFF);      // 256 x {mean, scale}
  float* out = (float*)d_out;
  hipFuncSetAttribute((const void*)k_corr, hipFuncAttributeMaxDynamicSharedMemorySize,
                      LDS_BYTES);
  k_stat<<<dim3(256), dim3(256), 0, stream>>>(x, stats);
  k_pack<<<dim3(296), dim3(512), 0, stream>>>(x, stats, pad);
  k_corr<<<dim3(256), dim3(512), LDS_BYTES, stream>>>(pad, out);
}